// Round 3
// baseline (1630.250 us; speedup 1.0000x reference)
//
#include <hip/hip_runtime.h>
#include <hip/hip_bf16.h>
#include <stdint.h>
#include <stddef.h>

// Problem dims
#define BATCH 1024
#define TSEQ  99      // SEQ_LEN-1 steps
#define HID   256
#define GDIM  1024    // 4*HID
#define EDIM  128
#define VOC   410
#define NT_FC 26      // ceil(410/16) -> padded 416

typedef __attribute__((ext_vector_type(8))) short short8;
typedef __attribute__((ext_vector_type(4))) float floatx4;

#define LOG2E 1.4426950408889634f

__device__ __forceinline__ short f2bf(float x) {
    union { float f; uint32_t u; } v; v.f = x;
    uint32_t r = (v.u + 0x7fffu + ((v.u >> 16) & 1u)) >> 16;
    return (short)r;
}

__device__ __forceinline__ float fexp2(float x) {
#if __has_builtin(__builtin_amdgcn_exp2f)
    return __builtin_amdgcn_exp2f(x);
#else
    return __exp2f(x);
#endif
}
__device__ __forceinline__ float frcp(float x) {
#if __has_builtin(__builtin_amdgcn_rcpf)
    return __builtin_amdgcn_rcpf(x);
#else
    return 1.f / x;
#endif
}
__device__ __forceinline__ float sigm(float x) {
    return frcp(1.f + fexp2(-LOG2E * x));
}
__device__ __forceinline__ float tanh_fast(float x) {
    x = fminf(fmaxf(x, -16.f), 16.f);
    float t = fexp2((2.f * LOG2E) * x);
    return (t - 1.f) * frcp(t + 1.f);
}

// ---------------------------------------------------------------------------
// enc[b][h] = b_enc[h] + sum_k encoder_out[b][k] * W_enc[h][k]
__global__ void k_enc(const float* __restrict__ x, const float* __restrict__ W,
                      const float* __restrict__ bias, float* __restrict__ enc) {
    __shared__ float xl[8 * 256];
    const int tid = threadIdx.x;
    const int b0 = blockIdx.x * 8;
#pragma unroll
    for (int i = 0; i < 8; ++i) xl[i * 256 + tid] = x[(b0 + i) * 256 + tid];
    __syncthreads();
    const int h = tid;
    float acc[8];
    const float bh = bias[h];
#pragma unroll
    for (int i = 0; i < 8; ++i) acc[i] = bh;
    for (int k = 0; k < 256; k += 4) {
        floatx4 w4 = *(const floatx4*)&W[h * 256 + k];
#pragma unroll
        for (int i = 0; i < 8; ++i) {
            floatx4 x4 = *(const floatx4*)&xl[i * 256 + k];
            acc[i] += w4[0] * x4[0] + w4[1] * x4[1] + w4[2] * x4[2] + w4[3] * x4[3];
        }
    }
#pragma unroll
    for (int i = 0; i < 8; ++i) enc[(b0 + i) * 256 + h] = acc[i];
}

// ---------------------------------------------------------------------------
// genc[b][g] = b_ih[g]+b_hh[g] + sum_k enc[b][k] * W_ih[g][128+k]
__global__ void k_genc(const float* __restrict__ enc, const float* __restrict__ W_ih,
                       const float* __restrict__ b_ih, const float* __restrict__ b_hh,
                       float* __restrict__ genc) {
    __shared__ float el[8 * 256];
    const int bg = blockIdx.x >> 2;
    const int gc = blockIdx.x & 3;
    const int tid = threadIdx.x;
    const int b0 = bg * 8;
#pragma unroll
    for (int i = 0; i < 8; ++i) el[i * 256 + tid] = enc[(b0 + i) * 256 + tid];
    __syncthreads();
    const int g = gc * 256 + tid;
    float acc[8];
    const float bb = b_ih[g] + b_hh[g];
#pragma unroll
    for (int i = 0; i < 8; ++i) acc[i] = bb;
    for (int k = 0; k < 256; k += 4) {
        floatx4 w4 = *(const floatx4*)&W_ih[g * 384 + 128 + k];
#pragma unroll
        for (int i = 0; i < 8; ++i) {
            floatx4 e4 = *(const floatx4*)&el[i * 256 + k];
            acc[i] += w4[0] * e4[0] + w4[1] * e4[1] + w4[2] * e4[2] + w4[3] * e4[3];
        }
    }
#pragma unroll
    for (int i = 0; i < 8; ++i) genc[(b0 + i) * 1024 + g] = acc[i];
}

// ---------------------------------------------------------------------------
// embW[v][g] = sum_e emb[v][e] * W_ih[g][e]   (e < 128)
__global__ void k_embW(const float* __restrict__ emb, const float* __restrict__ W_ih,
                       float* __restrict__ embW) {
    __shared__ float el[128];
    const int v = blockIdx.x, tid = threadIdx.x;
    if (tid < 128) el[tid] = emb[v * 128 + tid];
    __syncthreads();
    float acc[4] = {0.f, 0.f, 0.f, 0.f};
    for (int k = 0; k < 128; k += 4) {
        floatx4 e4 = *(const floatx4*)&el[k];
#pragma unroll
        for (int j = 0; j < 4; ++j) {
            floatx4 w4 = *(const floatx4*)&W_ih[(tid + 256 * j) * 384 + k];
            acc[j] += w4[0] * e4[0] + w4[1] * e4[1] + w4[2] * e4[2] + w4[3] * e4[3];
        }
    }
#pragma unroll
    for (int j = 0; j < 4; ++j) embW[v * 1024 + tid + 256 * j] = acc[j];
}

// ---------------------------------------------------------------------------
// Cast W_hh / W_fc to bf16 in MFMA B-fragment order:
// frag[((nt*8+kt)*64+lane)*8 + j] = W[n = nt*16+(lane&15)][k = kt*32+(lane>>4)*8+j]
__global__ void k_frag(const float* __restrict__ W_hh, const float* __restrict__ W_fc,
                       short* __restrict__ whh_frag, short* __restrict__ wfc_frag) {
    const int idx = blockIdx.x * 256 + threadIdx.x;
    if (idx < 64 * 8 * 64) {
        const int l = idx & 63, kt = (idx >> 6) & 7, nt = idx >> 9;
        const int g = nt * 16 + (l & 15);
        const int kb = kt * 32 + (l >> 4) * 8;
        short8 o;
#pragma unroll
        for (int j = 0; j < 8; ++j) o[j] = f2bf(W_hh[g * 256 + kb + j]);
        *(short8*)(whh_frag + (size_t)idx * 8) = o;
    } else {
        const int i2 = idx - 64 * 8 * 64;
        if (i2 < NT_FC * 8 * 64) {
            const int l = i2 & 63, kt = (i2 >> 6) & 7, nt = i2 >> 9;
            const int v = nt * 16 + (l & 15);
            const int kb = kt * 32 + (l >> 4) * 8;
            short8 o;
#pragma unroll
            for (int j = 0; j < 8; ++j)
                o[j] = (v < VOC) ? f2bf(W_fc[v * 256 + kb + j]) : (short)0;
            *(short8*)(wfc_frag + (size_t)i2 * 8) = o;
        }
    }
}

// ---------------------------------------------------------------------------
// Persistent LSTM, register-resident weights, 4-WG unit-split per batch-group.
// grid 256 WGs x 256 thr: group = blockIdx/4 (16 batch rows), j = blockIdx%4
// owns units [j*64, j*64+64). Wave w: column c=j*4+w -> ntiles {q*16+c},
// 32 B-fragments = 128 VGPRs held across all 99 steps.
// Cross-WG h exchange via agent-scope (IC-coherent) stores/loads + per-group
// monotonic flag (4 increments per step).
__global__ __launch_bounds__(256, 2) void k_lstm(
    const float* __restrict__ genc, const float* __restrict__ embW,
    const short* __restrict__ whh_frag, const int* __restrict__ targets,
    short* __restrict__ hs, unsigned short* hx, int* flags) {
    __shared__ short hsl[16 * 64];  // this WG's h slice: [row][u_local]
    const int tid = threadIdx.x;
    const int wv = tid >> 6, lane = tid & 63;
    const int q16 = lane >> 4, l16 = lane & 15;
    const int grp = blockIdx.x >> 2, j = blockIdx.x & 3;
    const int b0 = grp * 16;
    const int c = j * 4 + wv;        // column 0..15
    const int cu = c * 16 + l16;     // this lane's unit

    // ---- load weights into registers (once) ----
    short8 wfrag[4][8];
#pragma unroll
    for (int q = 0; q < 4; ++q)
#pragma unroll
        for (int kt = 0; kt < 8; ++kt)
            wfrag[q][kt] = *(const short8*)(whh_frag +
                ((size_t)((q * 16 + c) * 8 + kt) * 64 + lane) * 8);

    // ---- preload genc gate biases (t-invariant) ----
    float gbias[4][4];
#pragma unroll
    for (int q = 0; q < 4; ++q)
#pragma unroll
        for (int r = 0; r < 4; ++r)
            gbias[q][r] = genc[(size_t)(b0 + q16 * 4 + r) * GDIM + q * 256 + cu];

    float cst[4] = {0.f, 0.f, 0.f, 0.f};

    int tok[4];
#pragma unroll
    for (int r = 0; r < 4; ++r) tok[r] = targets[(b0 + q16 * 4 + r) * 100];

    int* flagp = flags + grp;
    const size_t hxg = (size_t)grp * 4096;

    for (int t = 0; t < TSEQ; ++t) {
        // embW gate biases for this step (independent of h -> issue before spin)
        float ge[4][4];
#pragma unroll
        for (int q = 0; q < 4; ++q)
#pragma unroll
            for (int r = 0; r < 4; ++r)
                ge[q][r] = embW[(size_t)tok[r] * GDIM + q * 256 + cu];

        // wait for all 4 WGs of the group to have published h(t-1)
        if (t > 0) {
            if (tid == 0) {
                const int need = 4 * t;
                int it = 0;
                while (__hip_atomic_load(flagp, __ATOMIC_RELAXED,
                                         __HIP_MEMORY_SCOPE_AGENT) < need &&
                       ++it < (1 << 22)) {
                    __builtin_amdgcn_s_sleep(2);
                }
            }
        }
        __syncthreads();

        // A-fragments: full h(t-1) via agent-scope (IC) loads
        const unsigned short* hb = hx + (size_t)(t & 1) * 262144 + hxg;
        short8 afrag[8];
#pragma unroll
        for (int kt = 0; kt < 8; ++kt) {
            union { unsigned long long q[2]; short8 s; } u;
            const unsigned long long* p = (const unsigned long long*)
                (hb + l16 * 256 + kt * 32 + q16 * 8);
            u.q[0] = __hip_atomic_load(p,     __ATOMIC_RELAXED, __HIP_MEMORY_SCOPE_AGENT);
            u.q[1] = __hip_atomic_load(p + 1, __ATOMIC_RELAXED, __HIP_MEMORY_SCOPE_AGENT);
            afrag[kt] = u.s;
        }

        // prefetch next tokens
        int tokn[4];
        if (t < TSEQ - 1) {
#pragma unroll
            for (int r = 0; r < 4; ++r)
                tokn[r] = targets[(b0 + q16 * 4 + r) * 100 + t + 1];
        }

        // MFMA: 4 ntiles x 8 kt, weights from registers
        floatx4 acc[4];
#pragma unroll
        for (int q = 0; q < 4; ++q) {
            floatx4 a = {0.f, 0.f, 0.f, 0.f};
#pragma unroll
            for (int kt = 0; kt < 8; ++kt)
                a = __builtin_amdgcn_mfma_f32_16x16x32_bf16(afrag[kt], wfrag[q][kt], a, 0, 0, 0);
            acc[q] = a;
        }

        // elementwise tail -> LDS slice
#pragma unroll
        for (int r = 0; r < 4; ++r) {
            float gi = acc[0][r] + gbias[0][r] + ge[0][r];
            float gf = acc[1][r] + gbias[1][r] + ge[1][r];
            float gg = acc[2][r] + gbias[2][r] + ge[2][r];
            float go = acc[3][r] + gbias[3][r] + ge[3][r];
            float i_ = sigm(gi);
            float f_ = sigm(gf);
            float g_ = tanh_fast(gg);
            float o_ = sigm(go);
            float cc = f_ * cst[r] + i_ * g_;
            cst[r] = cc;
            float h = o_ * tanh_fast(cc);
            hsl[(q16 * 4 + r) * 64 + wv * 16 + l16] = f2bf(h);
        }
        __syncthreads();

        // cooperative export: 2KB slice, 8B per lane
        const int row = tid >> 4, seg = tid & 15;
        unsigned long long v = *(const unsigned long long*)&hsl[row * 64 + seg * 4];
        // hs output (plain store, [b][t][u])
        *(unsigned long long*)(hs + ((size_t)(b0 + row) * TSEQ + t) * HID + j * 64 + seg * 4) = v;
        if (t < TSEQ - 1) {
            // publish to exchange buffer (agent scope -> IC)
            unsigned long long* dst = (unsigned long long*)
                (hx + (size_t)((t + 1) & 1) * 262144 + hxg + row * 256 + j * 64 + seg * 4);
            __hip_atomic_store(dst, v, __ATOMIC_RELAXED, __HIP_MEMORY_SCOPE_AGENT);
            __syncthreads();  // each wave drains its own vmcnt before barrier
            if (tid == 0)
                __hip_atomic_fetch_add(flagp, 1, __ATOMIC_RELEASE, __HIP_MEMORY_SCOPE_AGENT);
        }
#pragma unroll
        for (int r = 0; r < 4; ++r) tok[r] = tokn[r];
    }
}

// ---------------------------------------------------------------------------
// logits[r][v] = b_fc[v] + sum_k hs[r][k] * W_fc[v][k], r = b*99+t
__global__ __launch_bounds__(256, 2) void k_logits(
    const short* __restrict__ hs, const short* __restrict__ wfc_frag,
    const float* __restrict__ b_fc, float* __restrict__ out) {
    const int tid = threadIdx.x;
    const int w = tid >> 6, lane = tid & 63;
    const int q16 = lane >> 4, l16 = lane & 15;
    const long mbase = (long)blockIdx.x * 64 + w * 16;

    short8 afrag[8];
#pragma unroll
    for (int kt = 0; kt < 8; ++kt)
        afrag[kt] = *(const short8*)(hs + (mbase + l16) * HID + kt * 32 + q16 * 8);

#pragma unroll 1
    for (int nt = 0; nt < NT_FC; ++nt) {
        floatx4 a = {0.f, 0.f, 0.f, 0.f};
#pragma unroll
        for (int kt = 0; kt < 8; ++kt) {
            short8 bfrag = *(const short8*)(wfc_frag + ((size_t)(nt * 8 + kt) * 64 + lane) * 8);
            a = __builtin_amdgcn_mfma_f32_16x16x32_bf16(afrag[kt], bfrag, a, 0, 0, 0);
        }
        const int v = nt * 16 + l16;
        if (v < VOC) {
            const float bias = b_fc[v];
#pragma unroll
            for (int r = 0; r < 4; ++r) {
                const long row = mbase + q16 * 4 + r;
                out[row * VOC + v] = a[r] + bias;
            }
        }
    }
}

// ---------------------------------------------------------------------------
extern "C" void kernel_launch(void* const* d_in, const int* in_sizes, int n_in,
                              void* d_out, int out_size, void* d_ws, size_t ws_size,
                              hipStream_t stream) {
    const float* encoder_out = (const float*)d_in[0];
    const int*   targets     = (const int*)d_in[1];
    const float* emb         = (const float*)d_in[2];
    const float* W_enc       = (const float*)d_in[3];
    const float* b_enc       = (const float*)d_in[4];
    const float* W_ih        = (const float*)d_in[5];
    const float* W_hh        = (const float*)d_in[6];
    const float* b_ih        = (const float*)d_in[7];
    const float* b_hh        = (const float*)d_in[8];
    const float* W_fc        = (const float*)d_in[9];
    const float* b_fc        = (const float*)d_in[10];
    float* out = (float*)d_out;

    char* ws = (char*)d_ws;
    // enc region [0, 1MB) is DEAD after k_genc -> reused as hx (2 x 512KB)
    float* enc      = (float*)(ws + 0);
    unsigned short* hx = (unsigned short*)(ws + 0);
    float* genc     = (float*)(ws + 1048576);              // 4,194,304 B
    float* embW     = (float*)(ws + 5242880);              // 1,679,360 B
    short* whh_frag = (short*)(ws + 6922240);              //   524,288 B
    short* wfc_frag = (short*)(ws + 7446528);              //   212,992 B
    short* hs       = (short*)(ws + 7659520);              // 51,904,512 B
    int*   flags    = (int*)(ws + 59564032);               //       256 B

    k_enc<<<128, 256, 0, stream>>>(encoder_out, W_enc, b_enc, enc);
    k_genc<<<512, 256, 0, stream>>>(enc, W_ih, b_ih, b_hh, genc);
    // enc now dead; zero hx buffer0 (h(-1) = 0) and flags (stream-ordered)
    hipMemsetAsync(ws, 0, 524288, stream);
    hipMemsetAsync(flags, 0, 256, stream);
    k_embW<<<410, 256, 0, stream>>>(emb, W_ih, embW);
    k_frag<<<180, 256, 0, stream>>>(W_hh, W_fc, whh_frag, wfc_frag);
    k_lstm<<<256, 256, 0, stream>>>(genc, embW, whh_frag, targets, hs, hx, flags);
    k_logits<<<1584, 256, 0, stream>>>(hs, wfc_frag, b_fc, out);
}